// Round 2
// baseline (168.424 us; speedup 1.0000x reference)
//
#include <hip/hip_runtime.h>

#define NSAMP 65536
#define EMBED 256
#define ITERS 4   // sample-pairs per wave: 8192 waves * 4 = 32768 pairs = 65536 samples

// ---------------- phase 1: h[s][q] = 0.5*(x[s]·W1[q] + b1[q]) ----------------
__global__ __launch_bounds__(256, 8) void h_kernel(
    const float* __restrict__ x, const float* __restrict__ W1,
    const float* __restrict__ b1, float* __restrict__ hh)
{
    const int t = blockIdx.x * 256 + threadIdx.x;   // 524288 threads = 65536 s * 8 q
    const int s = t >> 3, q = t & 7;
    const float4* xr = (const float4*)(x + (size_t)s * EMBED);
    const float4* wr = (const float4*)(W1 + q * EMBED);
    float acc = 0.f;
#pragma unroll 8
    for (int e = 0; e < 64; ++e) {
        float4 a = xr[e], b = wr[e];
        acc += a.x * b.x + a.y * b.y + a.z * b.z + a.w * b.w;
    }
    hh[t] = 0.5f * (acc + b1[q]);   // half-angle
}

// ---------------- phase 2: circuit + out = z·W2^T + b2 ----------------
// Layout: 2 samples/wave (lanes 0-31 = A, 32-63 = B). idx bits {7,6,5} = reg r2r1r0,
// bits {4..0} = lane&31. Lane holds 8 complex amps sxv/syv[r].
__device__ inline float rfl(float v) {
    return __uint_as_float(__builtin_amdgcn_readfirstlane(__float_as_uint(v)));
}

// RX in stored coords: partner = reg r^KM, lane^LM. new = c*mine - i*s*partner.
#define RX3(KM, LM, CC, SS) do {                                              \
    float ux[8], uy[8];                                                       \
    _Pragma("unroll")                                                         \
    for (int r = 0; r < 8; ++r) {                                             \
        float tx = sxv[r ^ (KM)], ty = syv[r ^ (KM)];                         \
        if ((LM) != 0) { tx = __shfl_xor(tx, (LM), 64);                       \
                         ty = __shfl_xor(ty, (LM), 64); }                     \
        ux[r] = tx; uy[r] = ty;                                               \
    }                                                                         \
    _Pragma("unroll")                                                         \
    for (int r = 0; r < 8; ++r) {                                             \
        sxv[r] = (CC) * sxv[r] + (SS) * uy[r];                                \
        syv[r] = (CC) * syv[r] - (SS) * ux[r];                                \
    }                                                                         \
} while (0)

__global__ __launch_bounds__(256, 4) void circ_kernel(
    const float* __restrict__ hh,   // (65536, 8) half-angles
    const float* __restrict__ qw,   // (2, 8)
    const float* __restrict__ W2,   // (256, 8)
    const float* __restrict__ b2,   // (256,)
    float* __restrict__ out)        // (65536, 256)
{
    const int lane = threadIdx.x & 63;
    const int l5   = lane & 31;
    const int half = lane >> 5;
    const int own  = lane & 7;
    const int wid  = blockIdx.x * 4 + (threadIdx.x >> 6);

    // gate angles -> SGPRs (wave-uniform)
    float qc[16], qs[16];
#pragma unroll
    for (int i = 0; i < 16; ++i) {
        float th = 0.5f * qw[i];
        qc[i] = rfl(__cosf(th));
        qs[i] = rfl(__sinf(th));
    }

    // W2 slice for e = 4*lane+j, b2
    float w2r[4][8];
#pragma unroll
    for (int j = 0; j < 4; ++j)
#pragma unroll
        for (int q = 0; q < 8; ++q)
            w2r[j][q] = W2[(4 * lane + j) * 8 + q];
    const float4 b2c = *(const float4*)(b2 + 4 * lane);

    // measurement signs on lane5 bits (T-row lane parts) and r-parity selector
    const int lm5[8] = {0x15, 0x1F, 0x1F, 0x0F, 0x17, 0x0B, 0x15, 0x0A};
    float sg[8];
#pragma unroll
    for (int q = 0; q < 8; ++q)
        sg[q] = (__popc(l5 & lm5[q]) & 1) ? -1.0f : 1.0f;

    const int wl5 = __popc(l5);
    const int bbase = lane & 0x38;   // bpermute base for h broadcast

    for (int it = 0; it < ITERS; ++it) {
        const int pair = wid * ITERS + it;          // 0..32767
        const int s = 2 * pair + half;

        // own-q half-angle -> sincos -> broadcast all 8 (c,s) pairs
        const float hv = hh[s * 8 + own];
        const float co = __cosf(hv), so = __sinf(hv);
        float hcq[8], hsq[8];
#pragma unroll
        for (int q = 0; q < 8; ++q) {
            hcq[q] = __shfl(co, bbase | q, 64);
            hsq[q] = __shfl(so, bbase | q, 64);
        }

        // product-state init. qubits: q0,q1,q2 -> r2,r1,r0 ; q3..q7 -> lane bits 4..0
        float m5 = ((l5 >> 4) & 1 ? hsq[3] : hcq[3]);
        m5 *= ((l5 >> 3) & 1 ? hsq[4] : hcq[4]);
        m5 *= ((l5 >> 2) & 1 ? hsq[5] : hcq[5]);
        m5 *= ((l5 >> 1) & 1 ? hsq[6] : hcq[6]);
        m5 *= ((l5 >> 0) & 1 ? hsq[7] : hcq[7]);
        const float t00 = hcq[0] * hcq[1], t01 = hcq[0] * hsq[1];
        const float t10 = hsq[0] * hcq[1], t11 = hsq[0] * hsq[1];
        float kf[8] = { t00 * hcq[2], t00 * hsq[2], t01 * hcq[2], t01 * hsq[2],
                        t10 * hcq[2], t10 * hsq[2], t11 * hcq[2], t11 * hsq[2] };
        const int pc[8] = {0, 1, 1, 2, 1, 2, 2, 3};   // popc(r)
        float sxv[8], syv[8];
#pragma unroll
        for (int r = 0; r < 8; ++r) {
            const float rr = m5 * kf[r];
            const int w = (wl5 + pc[r]) & 3;
            sxv[r] = (w == 0) ? rr : ((w == 2) ? -rr : 0.0f);
            syv[r] = (w == 1) ? -rr : ((w == 3) ? rr : 0.0f);
        }

        // layer A (qw[0]): masks e7..e0
        RX3(4, 0,  qc[0], qs[0]);
        RX3(2, 0,  qc[1], qs[1]);
        RX3(1, 0,  qc[2], qs[2]);
        RX3(0, 16, qc[3], qs[3]);
        RX3(0, 8,  qc[4], qs[4]);
        RX3(0, 4,  qc[5], qs[5]);
        RX3(0, 2,  qc[6], qs[6]);
        RX3(0, 1,  qc[7], qs[7]);
        // layer B (qw[1]): masks R^-1(e_{7-q})
        RX3(6, 0,  qc[8],  qs[8]);   // 0xC0
        RX3(3, 0,  qc[9],  qs[9]);   // 0x60
        RX3(1, 16, qc[10], qs[10]);  // 0x30
        RX3(0, 24, qc[11], qs[11]);  // 0x18
        RX3(0, 12, qc[12], qs[12]);  // 0x0C
        RX3(0, 6,  qc[13], qs[13]);  // 0x06
        RX3(0, 3,  qc[14], qs[14]);  // 0x03
        RX3(6, 1,  qc[15], qs[15]);  // 0xC1

        // measurement: per-lane r-parity combos, sign by lane5 masks
        float p[8];
#pragma unroll
        for (int r = 0; r < 8; ++r) p[r] = sxv[r] * sxv[r] + syv[r] * syv[r];
        const float P6 = (p[0] + p[1] + p[6] + p[7]) - (p[2] + p[3] + p[4] + p[5]);
        const float P5 = (p[0] + p[2] + p[5] + p[7]) - (p[1] + p[3] + p[4] + p[6]);
        const float P2 = (p[0] + p[1] + p[4] + p[5]) - (p[2] + p[3] + p[6] + p[7]);
        float z0 = sg[0] * P6, z1 = sg[1] * P5, z2 = sg[2] * P2, z3 = sg[3] * P5;
        float z4 = sg[4] * P2, z5 = sg[5] * P5, z6 = sg[6] * P2, z7 = sg[7] * P5;

        // reduce 8 values over 32 lanes: recursive halving (bits 0..2) + butterfly (3,4)
        const bool c0 = lane & 1, c1 = lane & 2, c2 = lane & 4;
        float k0 = c0 ? z1 : z0, s0 = c0 ? z0 : z1; k0 += __shfl_xor(s0, 1, 64);
        float k1 = c0 ? z3 : z2, s1 = c0 ? z2 : z3; k1 += __shfl_xor(s1, 1, 64);
        float k2 = c0 ? z5 : z4, s2 = c0 ? z4 : z5; k2 += __shfl_xor(s2, 1, 64);
        float k3 = c0 ? z7 : z6, s3 = c0 ? z6 : z7; k3 += __shfl_xor(s3, 1, 64);
        float m0 = c1 ? k1 : k0, u0 = c1 ? k0 : k1; m0 += __shfl_xor(u0, 2, 64);
        float m1 = c1 ? k3 : k2, u1 = c1 ? k2 : k3; m1 += __shfl_xor(u1, 2, 64);
        float w  = c2 ? m1 : m0, v0 = c2 ? m0 : m1; w += __shfl_xor(v0, 4, 64);
        w += __shfl_xor(w, 8, 64);
        w += __shfl_xor(w, 16, 64);   // lane holds z_final[lane&7] of its sample

        // broadcast both samples' z to all lanes
        float zA[8], zB[8];
#pragma unroll
        for (int q = 0; q < 8; ++q) {
            const int srcA = (lane & 0x18) | q;
            zA[q] = __shfl(w, srcA, 64);
            zB[q] = __shfl(w, srcA + 32, 64);
        }

        // out = z·W2^T + b2 (all 64 lanes per sample, e = 4*lane+j)
        float a0 = b2c.x, a1 = b2c.y, a2 = b2c.z, a3 = b2c.w;
        float o0 = b2c.x, o1 = b2c.y, o2 = b2c.z, o3 = b2c.w;
#pragma unroll
        for (int q = 0; q < 8; ++q) {
            a0 += zA[q] * w2r[0][q]; a1 += zA[q] * w2r[1][q];
            a2 += zA[q] * w2r[2][q]; a3 += zA[q] * w2r[3][q];
            o0 += zB[q] * w2r[0][q]; o1 += zB[q] * w2r[1][q];
            o2 += zB[q] * w2r[2][q]; o3 += zB[q] * w2r[3][q];
        }
        *(float4*)(out + (size_t)(2 * pair) * EMBED + 4 * lane) =
            make_float4(a0, a1, a2, a3);
        *(float4*)(out + (size_t)(2 * pair + 1) * EMBED + 4 * lane) =
            make_float4(o0, o1, o2, o3);
    }
}

extern "C" void kernel_launch(void* const* d_in, const int* in_sizes, int n_in,
                              void* d_out, int out_size, void* d_ws, size_t ws_size,
                              hipStream_t stream) {
    const float* x  = (const float*)d_in[0];
    const float* W1 = (const float*)d_in[1];
    const float* b1 = (const float*)d_in[2];
    const float* qw = (const float*)d_in[3];
    const float* W2 = (const float*)d_in[4];
    const float* b2 = (const float*)d_in[5];
    float* out = (float*)d_out;
    float* hh  = (float*)d_ws;     // 65536*8 floats = 2 MB

    hipLaunchKernelGGL(h_kernel, dim3(2048), dim3(256), 0, stream, x, W1, b1, hh);
    hipLaunchKernelGGL(circ_kernel, dim3(2048), dim3(256), 0, stream,
                       hh, qw, W2, b2, out);
}

// Round 4
// 71.035 us; speedup vs baseline: 2.3710x; 2.3710x over previous
//
#include <hip/hip_runtime.h>

#define NSAMP 65536
#define EMBED 256
#define HITERS 4
#define CITERS 4

typedef _Float16 h2v __attribute__((ext_vector_type(2)));

__device__ inline float rfl(float v) {
    return __uint_as_float(__builtin_amdgcn_readfirstlane(__float_as_uint(v)));
}
template<int CTRL>
__device__ inline float dppf(float v) {
    return __int_as_float(__builtin_amdgcn_mov_dpp(__float_as_int(v), CTRL, 0xf, 0xf, true));
}
__device__ inline float2 unpk2(int u) {
    h2v h = __builtin_bit_cast(h2v, u);
    return make_float2((float)h.x, (float)h.y);
}
__device__ inline int pk2(float a, float b) {
    return __builtin_bit_cast(int, __builtin_amdgcn_cvt_pkrtz(a, b));
}
// quad_perm DPP controls: xor1=0xB1, xor2=0x4E, xor3=0x1B

// ---------------- phase 1: theta/2 -> packed (cos,sin) f16 ----------------
// wave handles 2 samples: reads 2 rows contiguously, 16-item halving reduce.
__global__ __launch_bounds__(256) void h_kernel(
    const float* __restrict__ x, const float* __restrict__ W1,
    const float* __restrict__ b1, int* __restrict__ hhu)
{
    const int lane = threadIdx.x & 63;
    const int wid  = blockIdx.x * 4 + (threadIdx.x >> 6);

    float4 w1c[8];
#pragma unroll
    for (int q = 0; q < 8; ++q)
        w1c[q] = *(const float4*)(W1 + q * EMBED + 4 * lane);
    const float b1h = 0.5f * b1[(lane >> 1) & 7];

    const bool s0 = lane & 1, s1 = lane & 2, s2 = lane & 4, s3 = lane & 8;

    for (int it = 0; it < HITERS; ++it) {
        const int p = wid * HITERS + it;          // pair index
        const float4 x0 = *(const float4*)(x + (size_t)p * 512 + 4 * lane);
        const float4 x1 = *(const float4*)(x + (size_t)p * 512 + 256 + 4 * lane);

        float vv[16];
#pragma unroll
        for (int q = 0; q < 8; ++q) {
            vv[2*q]   = x0.x*w1c[q].x + x0.y*w1c[q].y + x0.z*w1c[q].z + x0.w*w1c[q].w;
            vv[2*q+1] = x1.x*w1c[q].x + x1.y*w1c[q].y + x1.z*w1c[q].z + x1.w*w1c[q].w;
        }
#pragma unroll
        for (int i = 0; i < 8; ++i) {   // m=1 (DPP)
            float a = vv[2*i], b = vv[2*i+1];
            float keep = s0 ? b : a, send = s0 ? a : b;
            vv[i] = keep + dppf<0xB1>(send);
        }
#pragma unroll
        for (int i = 0; i < 4; ++i) {   // m=2 (DPP)
            float a = vv[2*i], b = vv[2*i+1];
            float keep = s1 ? b : a, send = s1 ? a : b;
            vv[i] = keep + dppf<0x4E>(send);
        }
#pragma unroll
        for (int i = 0; i < 2; ++i) {   // m=4
            float a = vv[2*i], b = vv[2*i+1];
            float keep = s2 ? b : a, send = s2 ? a : b;
            vv[i] = keep + __shfl_xor(send, 4, 64);
        }
        {                               // m=8
            float a = vv[0], b = vv[1];
            float keep = s3 ? b : a, send = s3 ? a : b;
            vv[0] = keep + __shfl_xor(send, 8, 64);
        }
        float r = vv[0];
        r += __shfl_xor(r, 16, 64);
        r += __shfl_xor(r, 32, 64);     // lane holds dot for (q=(lane>>1)&7, s=lane&1)

        const float th = 0.5f * r + b1h;           // half angle
        const int pk = pk2(__cosf(th), __sinf(th));
        if (lane < 16)
            hhu[p * 16 + (lane & 1) * 8 + (lane >> 1)] = pk;
    }
}

// ---------------- phase 2: circuit + out = z*W2^T + b2 ----------------
// 2 samples/wave. idx bits {7,6,5} = reg r, bits {4..0} = lane&31.

#define RX3_REG(KM, CC, SS) do {                                              \
    float ux[8], uy[8];                                                       \
    _Pragma("unroll")                                                         \
    for (int r = 0; r < 8; ++r) { ux[r] = sxv[r^(KM)]; uy[r] = syv[r^(KM)]; } \
    _Pragma("unroll")                                                         \
    for (int r = 0; r < 8; ++r) {                                             \
        float nx = (CC)*sxv[r] + (SS)*uy[r];                                  \
        float ny = (CC)*syv[r] - (SS)*ux[r];                                  \
        sxv[r] = nx; syv[r] = ny; }                                           \
} while (0)

#define RX3_DPP(KM, CTRL, CC, SS) do {                                        \
    float ux[8], uy[8];                                                       \
    _Pragma("unroll")                                                         \
    for (int r = 0; r < 8; ++r) {                                             \
        ux[r] = dppf<(CTRL)>(sxv[r^(KM)]);                                    \
        uy[r] = dppf<(CTRL)>(syv[r^(KM)]); }                                  \
    _Pragma("unroll")                                                         \
    for (int r = 0; r < 8; ++r) {                                             \
        float nx = (CC)*sxv[r] + (SS)*uy[r];                                  \
        float ny = (CC)*syv[r] - (SS)*ux[r];                                  \
        sxv[r] = nx; syv[r] = ny; }                                           \
} while (0)

#define RX3_F16(KM, LM, CC, SS) do {                                          \
    float ux[8], uy[8];                                                       \
    _Pragma("unroll")                                                         \
    for (int r = 0; r < 8; ++r) {                                             \
        int u = pk2(sxv[r^(KM)], syv[r^(KM)]);                                \
        u = __shfl_xor(u, (LM), 64);                                          \
        float2 pf = unpk2(u);                                                 \
        ux[r] = pf.x; uy[r] = pf.y; }                                         \
    _Pragma("unroll")                                                         \
    for (int r = 0; r < 8; ++r) {                                             \
        float nx = (CC)*sxv[r] + (SS)*uy[r];                                  \
        float ny = (CC)*syv[r] - (SS)*ux[r];                                  \
        sxv[r] = nx; syv[r] = ny; }                                           \
} while (0)

__global__ __launch_bounds__(256, 4) void circ_kernel(
    const int* __restrict__ hhu,    // (65536, 8) packed f16 (cos,sin) of half-angles
    const float* __restrict__ qw,   // (2, 8)
    const float* __restrict__ W2,   // (256, 8)
    const float* __restrict__ b2,   // (256,)
    float* __restrict__ out)        // (65536, 256)
{
    const int lane = threadIdx.x & 63;
    const int l5   = lane & 31;
    const int half = lane >> 5;
    const int w    = threadIdx.x >> 6;
    const int wid  = blockIdx.x * 4 + w;

    __shared__ float zb[4][2][8];

    // gate angles -> SGPRs
    float qc[16], qs[16];
#pragma unroll
    for (int i = 0; i < 16; ++i) {
        float th = 0.5f * qw[i];
        qc[i] = rfl(__cosf(th));
        qs[i] = rfl(__sinf(th));
    }

    float w2r[4][8];
#pragma unroll
    for (int j = 0; j < 4; ++j)
#pragma unroll
        for (int q = 0; q < 8; ++q)
            w2r[j][q] = W2[(4 * lane + j) * 8 + q];
    const float4 b2c = *(const float4*)(b2 + 4 * lane);

    const int lm5[8] = {0x15, 0x1F, 0x1F, 0x0F, 0x17, 0x0B, 0x15, 0x0A};
    float sg[8];
#pragma unroll
    for (int q = 0; q < 8; ++q)
        sg[q] = (__popc(l5 & lm5[q]) & 1) ? -1.0f : 1.0f;
    const int wl5 = __popc(l5);

    for (int it = 0; it < CITERS; ++it) {
        const int pair = wid * CITERS + it;
        const int s = 2 * pair + half;

        // load my sample's 8 packed (cos,sin) half-angle pairs
        const int4* hv = (const int4*)(hhu + (size_t)s * 8);
        const int4 u0 = hv[0], u1 = hv[1];
        float hcq[8], hsq[8];
#define UNPK(U, Q) do { float2 f = unpk2(U); hcq[Q] = f.x; hsq[Q] = f.y; } while (0)
        UNPK(u0.x, 0); UNPK(u0.y, 1); UNPK(u0.z, 2); UNPK(u0.w, 3);
        UNPK(u1.x, 4); UNPK(u1.y, 5); UNPK(u1.z, 6); UNPK(u1.w, 7);
#undef UNPK

        // product-state init: q0,q1,q2 -> r2,r1,r0 ; q3..q7 -> lane bits 4..0
        float m5 = ((l5 >> 4) & 1 ? hsq[3] : hcq[3]);
        m5 *= ((l5 >> 3) & 1 ? hsq[4] : hcq[4]);
        m5 *= ((l5 >> 2) & 1 ? hsq[5] : hcq[5]);
        m5 *= ((l5 >> 1) & 1 ? hsq[6] : hcq[6]);
        m5 *= ((l5 >> 0) & 1 ? hsq[7] : hcq[7]);
        const float t00 = hcq[0] * hcq[1], t01 = hcq[0] * hsq[1];
        const float t10 = hsq[0] * hcq[1], t11 = hsq[0] * hsq[1];
        float kf[8] = { t00 * hcq[2], t00 * hsq[2], t01 * hcq[2], t01 * hsq[2],
                        t10 * hcq[2], t10 * hsq[2], t11 * hcq[2], t11 * hsq[2] };
        const int pc[8] = {0, 1, 1, 2, 1, 2, 2, 3};
        float sxv[8], syv[8];
#pragma unroll
        for (int r = 0; r < 8; ++r) {
            const float rr = m5 * kf[r];
            const int ww = (wl5 + pc[r]) & 3;
            sxv[r] = (ww == 0) ? rr : ((ww == 2) ? -rr : 0.0f);
            syv[r] = (ww == 1) ? -rr : ((ww == 3) ? rr : 0.0f);
        }

        // layer A (qw[0]): masks e7..e0
        RX3_REG(4,        qc[0], qs[0]);
        RX3_REG(2,        qc[1], qs[1]);
        RX3_REG(1,        qc[2], qs[2]);
        RX3_F16(0, 16,    qc[3], qs[3]);
        RX3_F16(0, 8,     qc[4], qs[4]);
        RX3_F16(0, 4,     qc[5], qs[5]);
        RX3_DPP(0, 0x4E,  qc[6], qs[6]);   // xor2
        RX3_DPP(0, 0xB1,  qc[7], qs[7]);   // xor1
        // layer B (qw[1]): masks R^-1(e_{7-q})
        RX3_REG(6,        qc[8],  qs[8]);  // 0xC0
        RX3_REG(3,        qc[9],  qs[9]);  // 0x60
        RX3_F16(1, 16,    qc[10], qs[10]); // 0x30
        RX3_F16(0, 24,    qc[11], qs[11]); // 0x18
        RX3_F16(0, 12,    qc[12], qs[12]); // 0x0C
        RX3_F16(0, 6,     qc[13], qs[13]); // 0x06
        RX3_DPP(0, 0x1B,  qc[14], qs[14]); // 0x03 -> xor3
        RX3_DPP(6, 0xB1,  qc[15], qs[15]); // 0xC1 -> reg6 + xor1

        // measurement
        float p[8];
#pragma unroll
        for (int r = 0; r < 8; ++r) p[r] = sxv[r]*sxv[r] + syv[r]*syv[r];
        const float P6 = (p[0]+p[1]+p[6]+p[7]) - (p[2]+p[3]+p[4]+p[5]);
        const float P5 = (p[0]+p[2]+p[5]+p[7]) - (p[1]+p[3]+p[4]+p[6]);
        const float P2 = (p[0]+p[1]+p[4]+p[5]) - (p[2]+p[3]+p[6]+p[7]);
        float z0 = sg[0]*P6, z1 = sg[1]*P5, z2 = sg[2]*P2, z3 = sg[3]*P5;
        float z4 = sg[4]*P2, z5 = sg[5]*P5, z6 = sg[6]*P2, z7 = sg[7]*P5;

        // reduce 8 values over each 32-lane half
        const bool c0 = lane & 1, c1 = lane & 2, c2 = lane & 4;
        float k0 = c0 ? z1 : z0, t0 = c0 ? z0 : z1; k0 += dppf<0xB1>(t0);
        float k1 = c0 ? z3 : z2, t1 = c0 ? z2 : z3; k1 += dppf<0xB1>(t1);
        float k2 = c0 ? z5 : z4, t2 = c0 ? z4 : z5; k2 += dppf<0xB1>(t2);
        float k3 = c0 ? z7 : z6, t3 = c0 ? z6 : z7; k3 += dppf<0xB1>(t3);
        float m0 = c1 ? k1 : k0, v0 = c1 ? k0 : k1; m0 += dppf<0x4E>(v0);
        float m1 = c1 ? k3 : k2, v1 = c1 ? k2 : k3; m1 += dppf<0x4E>(v1);
        float wv = c2 ? m1 : m0, v2 = c2 ? m0 : m1; wv += __shfl_xor(v2, 4, 64);
        wv += __shfl_xor(wv, 8, 64);
        wv += __shfl_xor(wv, 16, 64);   // lane holds z[l5&7] of its sample

        // z broadcast via tiny LDS (same-wave write->read, no barrier needed)
        if (l5 < 8) zb[w][half][l5] = wv;
        const float4* zp = (const float4*)&zb[w][0][0];
        const float4 a0 = zp[0], a1 = zp[1], o0v = zp[2], o1v = zp[3];
        const float zA[8] = {a0.x, a0.y, a0.z, a0.w, a1.x, a1.y, a1.z, a1.w};
        const float zB[8] = {o0v.x, o0v.y, o0v.z, o0v.w, o1v.x, o1v.y, o1v.z, o1v.w};

        float a_0 = b2c.x, a_1 = b2c.y, a_2 = b2c.z, a_3 = b2c.w;
        float b_0 = b2c.x, b_1 = b2c.y, b_2 = b2c.z, b_3 = b2c.w;
#pragma unroll
        for (int q = 0; q < 8; ++q) {
            a_0 += zA[q] * w2r[0][q]; a_1 += zA[q] * w2r[1][q];
            a_2 += zA[q] * w2r[2][q]; a_3 += zA[q] * w2r[3][q];
            b_0 += zB[q] * w2r[0][q]; b_1 += zB[q] * w2r[1][q];
            b_2 += zB[q] * w2r[2][q]; b_3 += zB[q] * w2r[3][q];
        }
        *(float4*)(out + (size_t)(2 * pair) * EMBED + 4 * lane) =
            make_float4(a_0, a_1, a_2, a_3);
        *(float4*)(out + (size_t)(2 * pair + 1) * EMBED + 4 * lane) =
            make_float4(b_0, b_1, b_2, b_3);
    }
}

extern "C" void kernel_launch(void* const* d_in, const int* in_sizes, int n_in,
                              void* d_out, int out_size, void* d_ws, size_t ws_size,
                              hipStream_t stream) {
    const float* x  = (const float*)d_in[0];
    const float* W1 = (const float*)d_in[1];
    const float* b1 = (const float*)d_in[2];
    const float* qw = (const float*)d_in[3];
    const float* W2 = (const float*)d_in[4];
    const float* b2 = (const float*)d_in[5];
    float* out = (float*)d_out;
    int* hhu = (int*)d_ws;     // 65536*8 uints = 2 MB

    hipLaunchKernelGGL(h_kernel, dim3(2048), dim3(256), 0, stream, x, W1, b1, hhu);
    hipLaunchKernelGGL(circ_kernel, dim3(2048), dim3(256), 0, stream,
                       hhu, qw, W2, b2, out);
}

// Round 5
// 54.996 us; speedup vs baseline: 3.0625x; 1.2916x over previous
//
#include <hip/hip_runtime.h>

#define NSAMP 65536
#define EMBED 256
#define HITERS 4
#define CITERS 4

typedef _Float16 h2v __attribute__((ext_vector_type(2)));

__device__ inline float rfl(float v) {
    return __uint_as_float(__builtin_amdgcn_readfirstlane(__float_as_uint(v)));
}
template<int CTRL>
__device__ inline float dppf(float v) {
    return __int_as_float(__builtin_amdgcn_mov_dpp(__float_as_int(v), CTRL, 0xf, 0xf, true));
}
__device__ inline float2 unpk2(int u) {
    h2v h = __builtin_bit_cast(h2v, u);
    return make_float2((float)h.x, (float)h.y);
}
__device__ inline int pk2(float a, float b) {
    return __builtin_bit_cast(int, __builtin_amdgcn_cvt_pkrtz(a, b));
}
// quad_perm DPP controls: xor1=0xB1, xor2=0x4E, xor3=0x1B

// ---------------- phase 1: combined half-angles -> packed (cos,sin) f16 ----
// theta_q = x.W1_q + b1_q + qw[0][q]  (layer-1 RX folded: RX angles add).
__global__ __launch_bounds__(256) void h_kernel(
    const float* __restrict__ x, const float* __restrict__ W1,
    const float* __restrict__ b1, const float* __restrict__ qw,
    int* __restrict__ hhu)
{
    const int lane = threadIdx.x & 63;
    const int wid  = blockIdx.x * 4 + (threadIdx.x >> 6);

    float4 w1c[8];
#pragma unroll
    for (int q = 0; q < 8; ++q)
        w1c[q] = *(const float4*)(W1 + q * EMBED + 4 * lane);
    const int qq = (lane >> 1) & 7;
    const float b1h = 0.5f * (b1[qq] + qw[qq]);   // + layer-1 fixed angle

    const bool s0 = lane & 1, s1 = lane & 2, s2 = lane & 4, s3 = lane & 8;

    for (int it = 0; it < HITERS; ++it) {
        const int p = wid * HITERS + it;          // pair index
        const float4 x0 = *(const float4*)(x + (size_t)p * 512 + 4 * lane);
        const float4 x1 = *(const float4*)(x + (size_t)p * 512 + 256 + 4 * lane);

        float vv[16];
#pragma unroll
        for (int q = 0; q < 8; ++q) {
            vv[2*q]   = x0.x*w1c[q].x + x0.y*w1c[q].y + x0.z*w1c[q].z + x0.w*w1c[q].w;
            vv[2*q+1] = x1.x*w1c[q].x + x1.y*w1c[q].y + x1.z*w1c[q].z + x1.w*w1c[q].w;
        }
#pragma unroll
        for (int i = 0; i < 8; ++i) {   // m=1 (DPP)
            float a = vv[2*i], b = vv[2*i+1];
            float keep = s0 ? b : a, send = s0 ? a : b;
            vv[i] = keep + dppf<0xB1>(send);
        }
#pragma unroll
        for (int i = 0; i < 4; ++i) {   // m=2 (DPP)
            float a = vv[2*i], b = vv[2*i+1];
            float keep = s1 ? b : a, send = s1 ? a : b;
            vv[i] = keep + dppf<0x4E>(send);
        }
#pragma unroll
        for (int i = 0; i < 2; ++i) {   // m=4
            float a = vv[2*i], b = vv[2*i+1];
            float keep = s2 ? b : a, send = s2 ? a : b;
            vv[i] = keep + __shfl_xor(send, 4, 64);
        }
        {                               // m=8
            float a = vv[0], b = vv[1];
            float keep = s3 ? b : a, send = s3 ? a : b;
            vv[0] = keep + __shfl_xor(send, 8, 64);
        }
        float r = vv[0];
        r += __shfl_xor(r, 16, 64);
        r += __shfl_xor(r, 32, 64);     // lane holds dot for (q=(lane>>1)&7, s=lane&1)

        const float th = 0.5f * r + b1h;           // combined half angle
        const int pk = pk2(__cosf(th), __sinf(th));
        if (lane < 16)
            hhu[p * 16 + (lane & 1) * 8 + (lane >> 1)] = pk;
    }
}

// ---------------- phase 2: circuit (layer-2 only) + out = z*W2^T + b2 ------
// 2 samples/wave. idx bits {7,6,5} = reg r, bits {4..0} = lane&31.

#define RX3_REG(KM, CC, SS) do {                                              \
    float ux[8], uy[8];                                                       \
    _Pragma("unroll")                                                         \
    for (int r = 0; r < 8; ++r) { ux[r] = sxv[r^(KM)]; uy[r] = syv[r^(KM)]; } \
    _Pragma("unroll")                                                         \
    for (int r = 0; r < 8; ++r) {                                             \
        float nx = (CC)*sxv[r] + (SS)*uy[r];                                  \
        float ny = (CC)*syv[r] - (SS)*ux[r];                                  \
        sxv[r] = nx; syv[r] = ny; }                                           \
} while (0)

#define RX3_DPP(KM, CTRL, CC, SS) do {                                        \
    float ux[8], uy[8];                                                       \
    _Pragma("unroll")                                                         \
    for (int r = 0; r < 8; ++r) {                                             \
        ux[r] = dppf<(CTRL)>(sxv[r^(KM)]);                                    \
        uy[r] = dppf<(CTRL)>(syv[r^(KM)]); }                                  \
    _Pragma("unroll")                                                         \
    for (int r = 0; r < 8; ++r) {                                             \
        float nx = (CC)*sxv[r] + (SS)*uy[r];                                  \
        float ny = (CC)*syv[r] - (SS)*ux[r];                                  \
        sxv[r] = nx; syv[r] = ny; }                                           \
} while (0)

#define RX3_F16(KM, LM, CC, SS) do {                                          \
    float ux[8], uy[8];                                                       \
    _Pragma("unroll")                                                         \
    for (int r = 0; r < 8; ++r) {                                             \
        int u = pk2(sxv[r^(KM)], syv[r^(KM)]);                                \
        u = __shfl_xor(u, (LM), 64);                                          \
        float2 pf = unpk2(u);                                                 \
        ux[r] = pf.x; uy[r] = pf.y; }                                         \
    _Pragma("unroll")                                                         \
    for (int r = 0; r < 8; ++r) {                                             \
        float nx = (CC)*sxv[r] + (SS)*uy[r];                                  \
        float ny = (CC)*syv[r] - (SS)*ux[r];                                  \
        sxv[r] = nx; syv[r] = ny; }                                           \
} while (0)

__global__ __launch_bounds__(256, 4) void circ_kernel(
    const int* __restrict__ hhu,    // (65536, 8) packed f16 (cos,sin) of half-angles
    const float* __restrict__ qw,   // (2, 8)
    const float* __restrict__ W2,   // (256, 8)
    const float* __restrict__ b2,   // (256,)
    float* __restrict__ out)        // (65536, 256)
{
    const int lane = threadIdx.x & 63;
    const int l5   = lane & 31;
    const int half = lane >> 5;
    const int w    = threadIdx.x >> 6;
    const int wid  = blockIdx.x * 4 + w;

    __shared__ float zb[4][2][8];

    // layer-2 gate angles -> SGPRs
    float qc[8], qs[8];
#pragma unroll
    for (int i = 0; i < 8; ++i) {
        float th = 0.5f * qw[8 + i];
        qc[i] = rfl(__cosf(th));
        qs[i] = rfl(__sinf(th));
    }

    float w2r[4][8];
#pragma unroll
    for (int j = 0; j < 4; ++j)
#pragma unroll
        for (int q = 0; q < 8; ++q)
            w2r[j][q] = W2[(4 * lane + j) * 8 + q];
    const float4 b2c = *(const float4*)(b2 + 4 * lane);

    const int lm5[8] = {0x15, 0x1F, 0x1F, 0x0F, 0x17, 0x0B, 0x15, 0x0A};
    float sg[8];
#pragma unroll
    for (int q = 0; q < 8; ++q)
        sg[q] = (__popc(l5 & lm5[q]) & 1) ? -1.0f : 1.0f;
    const int wl5 = __popc(l5);

    for (int it = 0; it < CITERS; ++it) {
        const int pair = wid * CITERS + it;
        const int s = 2 * pair + half;

        // load my sample's 8 packed (cos,sin) half-angle pairs
        const int4* hv = (const int4*)(hhu + (size_t)s * 8);
        const int4 u0 = hv[0], u1 = hv[1];
        float hcq[8], hsq[8];
#define UNPK(U, Q) do { float2 f = unpk2(U); hcq[Q] = f.x; hsq[Q] = f.y; } while (0)
        UNPK(u0.x, 0); UNPK(u0.y, 1); UNPK(u0.z, 2); UNPK(u0.w, 3);
        UNPK(u1.x, 4); UNPK(u1.y, 5); UNPK(u1.z, 6); UNPK(u1.w, 7);
#undef UNPK

        // product-state init (data + layer-1 angles folded):
        // q0,q1,q2 -> r2,r1,r0 ; q3..q7 -> lane bits 4..0
        float m5 = ((l5 >> 4) & 1 ? hsq[3] : hcq[3]);
        m5 *= ((l5 >> 3) & 1 ? hsq[4] : hcq[4]);
        m5 *= ((l5 >> 2) & 1 ? hsq[5] : hcq[5]);
        m5 *= ((l5 >> 1) & 1 ? hsq[6] : hcq[6]);
        m5 *= ((l5 >> 0) & 1 ? hsq[7] : hcq[7]);
        const float t00 = hcq[0] * hcq[1], t01 = hcq[0] * hsq[1];
        const float t10 = hsq[0] * hcq[1], t11 = hsq[0] * hsq[1];
        float kf[8] = { t00 * hcq[2], t00 * hsq[2], t01 * hcq[2], t01 * hsq[2],
                        t10 * hcq[2], t10 * hsq[2], t11 * hcq[2], t11 * hsq[2] };
        const int pc[8] = {0, 1, 1, 2, 1, 2, 2, 3};
        float sxv[8], syv[8];
#pragma unroll
        for (int r = 0; r < 8; ++r) {
            const float rr = m5 * kf[r];
            const int ww = (wl5 + pc[r]) & 3;
            sxv[r] = (ww == 0) ? rr : ((ww == 2) ? -rr : 0.0f);
            syv[r] = (ww == 1) ? -rr : ((ww == 3) ? rr : 0.0f);
        }

        // layer 2 (qw[1]): masks R^-1(e_{7-q})
        RX3_REG(6,        qc[0], qs[0]);  // 0xC0
        RX3_REG(3,        qc[1], qs[1]);  // 0x60
        RX3_F16(1, 16,    qc[2], qs[2]);  // 0x30
        RX3_F16(0, 24,    qc[3], qs[3]);  // 0x18
        RX3_F16(0, 12,    qc[4], qs[4]);  // 0x0C
        RX3_F16(0, 6,     qc[5], qs[5]);  // 0x06
        RX3_DPP(0, 0x1B,  qc[6], qs[6]);  // 0x03 -> xor3
        RX3_DPP(6, 0xB1,  qc[7], qs[7]);  // 0xC1 -> reg6 + xor1

        // measurement
        float p[8];
#pragma unroll
        for (int r = 0; r < 8; ++r) p[r] = sxv[r]*sxv[r] + syv[r]*syv[r];
        const float P6 = (p[0]+p[1]+p[6]+p[7]) - (p[2]+p[3]+p[4]+p[5]);
        const float P5 = (p[0]+p[2]+p[5]+p[7]) - (p[1]+p[3]+p[4]+p[6]);
        const float P2 = (p[0]+p[1]+p[4]+p[5]) - (p[2]+p[3]+p[6]+p[7]);
        float z0 = sg[0]*P6, z1 = sg[1]*P5, z2 = sg[2]*P2, z3 = sg[3]*P5;
        float z4 = sg[4]*P2, z5 = sg[5]*P5, z6 = sg[6]*P2, z7 = sg[7]*P5;

        // reduce 8 values over each 32-lane half
        const bool c0 = lane & 1, c1 = lane & 2, c2 = lane & 4;
        float k0 = c0 ? z1 : z0, t0 = c0 ? z0 : z1; k0 += dppf<0xB1>(t0);
        float k1 = c0 ? z3 : z2, t1 = c0 ? z2 : z3; k1 += dppf<0xB1>(t1);
        float k2 = c0 ? z5 : z4, t2 = c0 ? z4 : z5; k2 += dppf<0xB1>(t2);
        float k3 = c0 ? z7 : z6, t3 = c0 ? z6 : z7; k3 += dppf<0xB1>(t3);
        float m0 = c1 ? k1 : k0, v0 = c1 ? k0 : k1; m0 += dppf<0x4E>(v0);
        float m1 = c1 ? k3 : k2, v1 = c1 ? k2 : k3; m1 += dppf<0x4E>(v1);
        float wv = c2 ? m1 : m0, v2 = c2 ? m0 : m1; wv += __shfl_xor(v2, 4, 64);
        wv += __shfl_xor(wv, 8, 64);
        wv += __shfl_xor(wv, 16, 64);   // lane holds z[l5&7] of its sample

        // z broadcast via tiny LDS (same-wave write->read, no barrier needed)
        if (l5 < 8) zb[w][half][l5] = wv;
        const float4* zp = (const float4*)&zb[w][0][0];
        const float4 a0 = zp[0], a1 = zp[1], o0v = zp[2], o1v = zp[3];
        const float zA[8] = {a0.x, a0.y, a0.z, a0.w, a1.x, a1.y, a1.z, a1.w};
        const float zB[8] = {o0v.x, o0v.y, o0v.z, o0v.w, o1v.x, o1v.y, o1v.z, o1v.w};

        float a_0 = b2c.x, a_1 = b2c.y, a_2 = b2c.z, a_3 = b2c.w;
        float b_0 = b2c.x, b_1 = b2c.y, b_2 = b2c.z, b_3 = b2c.w;
#pragma unroll
        for (int q = 0; q < 8; ++q) {
            a_0 += zA[q] * w2r[0][q]; a_1 += zA[q] * w2r[1][q];
            a_2 += zA[q] * w2r[2][q]; a_3 += zA[q] * w2r[3][q];
            b_0 += zB[q] * w2r[0][q]; b_1 += zB[q] * w2r[1][q];
            b_2 += zB[q] * w2r[2][q]; b_3 += zB[q] * w2r[3][q];
        }
        *(float4*)(out + (size_t)(2 * pair) * EMBED + 4 * lane) =
            make_float4(a_0, a_1, a_2, a_3);
        *(float4*)(out + (size_t)(2 * pair + 1) * EMBED + 4 * lane) =
            make_float4(b_0, b_1, b_2, b_3);
    }
}

extern "C" void kernel_launch(void* const* d_in, const int* in_sizes, int n_in,
                              void* d_out, int out_size, void* d_ws, size_t ws_size,
                              hipStream_t stream) {
    const float* x  = (const float*)d_in[0];
    const float* W1 = (const float*)d_in[1];
    const float* b1 = (const float*)d_in[2];
    const float* qw = (const float*)d_in[3];
    const float* W2 = (const float*)d_in[4];
    const float* b2 = (const float*)d_in[5];
    float* out = (float*)d_out;
    int* hhu = (int*)d_ws;     // 65536*8 uints = 2 MB

    hipLaunchKernelGGL(h_kernel, dim3(2048), dim3(256), 0, stream, x, W1, b1, qw, hhu);
    hipLaunchKernelGGL(circ_kernel, dim3(2048), dim3(256), 0, stream,
                       hhu, qw, W2, b2, out);
}

// Round 6
// 47.979 us; speedup vs baseline: 3.5104x; 1.1463x over previous
//
#include <hip/hip_runtime.h>

#define NSAMP 65536
#define EMBED 256
#define HITERS 4

typedef _Float16 h2v __attribute__((ext_vector_type(2)));

__device__ inline float rfl(float v) {
    return __uint_as_float(__builtin_amdgcn_readfirstlane(__float_as_uint(v)));
}
template<int CTRL>
__device__ inline float dppf(float v) {
    return __int_as_float(__builtin_amdgcn_mov_dpp(__float_as_int(v), CTRL, 0xf, 0xf, true));
}
__device__ inline float2 unpk2(int u) {
    h2v h = __builtin_bit_cast(h2v, u);
    return make_float2((float)h.x, (float)h.y);
}
__device__ inline int pk2(float a, float b) {
    return __builtin_bit_cast(int, __builtin_amdgcn_cvt_pkrtz(a, b));
}
// DPP ctrls: quad xor1=0xB1, xor2=0x4E, xor3=0x1B, row_ror:8=0x128 (xor8 in row16)

// ---------------- phase 1: combined half-angles -> packed (cos,sin) f16 ----
// theta_q = x.W1_q + b1_q + qw[0][q]  (layer-1 RX folded: RX angles add).
__global__ __launch_bounds__(256) void h_kernel(
    const float* __restrict__ x, const float* __restrict__ W1,
    const float* __restrict__ b1, const float* __restrict__ qw,
    int* __restrict__ hhu)
{
    const int lane = threadIdx.x & 63;
    const int wid  = blockIdx.x * 4 + (threadIdx.x >> 6);

    float4 w1c[8];
#pragma unroll
    for (int q = 0; q < 8; ++q)
        w1c[q] = *(const float4*)(W1 + q * EMBED + 4 * lane);
    const int qq = (lane >> 1) & 7;
    const float b1h = 0.5f * (b1[qq] + qw[qq]);   // + layer-1 fixed angle

    const bool s0 = lane & 1, s1 = lane & 2, s2 = lane & 4, s3 = lane & 8;

    for (int it = 0; it < HITERS; ++it) {
        const int p = wid * HITERS + it;          // pair index
        const float4 x0 = *(const float4*)(x + (size_t)p * 512 + 4 * lane);
        const float4 x1 = *(const float4*)(x + (size_t)p * 512 + 256 + 4 * lane);

        float vv[16];
#pragma unroll
        for (int q = 0; q < 8; ++q) {
            vv[2*q]   = x0.x*w1c[q].x + x0.y*w1c[q].y + x0.z*w1c[q].z + x0.w*w1c[q].w;
            vv[2*q+1] = x1.x*w1c[q].x + x1.y*w1c[q].y + x1.z*w1c[q].z + x1.w*w1c[q].w;
        }
#pragma unroll
        for (int i = 0; i < 8; ++i) {   // m=1 (DPP)
            float a = vv[2*i], b = vv[2*i+1];
            float keep = s0 ? b : a, send = s0 ? a : b;
            vv[i] = keep + dppf<0xB1>(send);
        }
#pragma unroll
        for (int i = 0; i < 4; ++i) {   // m=2 (DPP)
            float a = vv[2*i], b = vv[2*i+1];
            float keep = s1 ? b : a, send = s1 ? a : b;
            vv[i] = keep + dppf<0x4E>(send);
        }
#pragma unroll
        for (int i = 0; i < 2; ++i) {   // m=4
            float a = vv[2*i], b = vv[2*i+1];
            float keep = s2 ? b : a, send = s2 ? a : b;
            vv[i] = keep + __shfl_xor(send, 4, 64);
        }
        {                               // m=8
            float a = vv[0], b = vv[1];
            float keep = s3 ? b : a, send = s3 ? a : b;
            vv[0] = keep + __shfl_xor(send, 8, 64);
        }
        float r = vv[0];
        r += __shfl_xor(r, 16, 64);
        r += __shfl_xor(r, 32, 64);     // lane holds dot for (q=(lane>>1)&7, s=lane&1)

        const float th = 0.5f * r + b1h;           // combined half angle
        const int pk = pk2(__cosf(th), __sinf(th));
        if (lane < 16)
            hhu[p * 16 + (lane & 1) * 8 + (lane >> 1)] = pk;
    }
}

// ---------------- phase 2: circuit (layer-2 only) + out = z*W2^T + b2 ------
// 4 samples/wave, 16 lanes each. idx bits {7..4} = reg r (qubits 0-3),
// bits {3..0} = lane&15 (qubits 4-7). Lane holds 16 complex amps.

#define RX4_REG(KM, CC, SS) do {                                              \
    float ux[16], uy[16];                                                     \
    _Pragma("unroll")                                                         \
    for (int r = 0; r < 16; ++r) { ux[r] = sxv[r^(KM)]; uy[r] = syv[r^(KM)]; }\
    _Pragma("unroll")                                                         \
    for (int r = 0; r < 16; ++r) {                                            \
        float nx = (CC)*sxv[r] + (SS)*uy[r];                                  \
        float ny = (CC)*syv[r] - (SS)*ux[r];                                  \
        sxv[r] = nx; syv[r] = ny; }                                           \
} while (0)

#define RX4_DPP(KM, CTRL, CC, SS) do {                                        \
    float ux[16], uy[16];                                                     \
    _Pragma("unroll")                                                         \
    for (int r = 0; r < 16; ++r) {                                            \
        ux[r] = dppf<(CTRL)>(sxv[r^(KM)]);                                    \
        uy[r] = dppf<(CTRL)>(syv[r^(KM)]); }                                  \
    _Pragma("unroll")                                                         \
    for (int r = 0; r < 16; ++r) {                                            \
        float nx = (CC)*sxv[r] + (SS)*uy[r];                                  \
        float ny = (CC)*syv[r] - (SS)*ux[r];                                  \
        sxv[r] = nx; syv[r] = ny; }                                           \
} while (0)

#define RX4_F16(KM, LM, CC, SS) do {                                          \
    float ux[16], uy[16];                                                     \
    _Pragma("unroll")                                                         \
    for (int r = 0; r < 16; ++r) {                                            \
        int u = pk2(sxv[r^(KM)], syv[r^(KM)]);                                \
        u = __shfl_xor(u, (LM), 64);                                          \
        float2 pf = unpk2(u);                                                 \
        ux[r] = pf.x; uy[r] = pf.y; }                                         \
    _Pragma("unroll")                                                         \
    for (int r = 0; r < 16; ++r) {                                            \
        float nx = (CC)*sxv[r] + (SS)*uy[r];                                  \
        float ny = (CC)*syv[r] - (SS)*ux[r];                                  \
        sxv[r] = nx; syv[r] = ny; }                                           \
} while (0)

__global__ __launch_bounds__(256, 4) void circ_kernel(
    const int* __restrict__ hhu,    // (65536, 8) packed f16 (cos,sin) of half-angles
    const float* __restrict__ qw,   // (2, 8)
    const float* __restrict__ W2,   // (256, 8)
    const float* __restrict__ b2,   // (256,)
    float* __restrict__ out)        // (65536, 256)
{
    const int lane = threadIdx.x & 63;
    const int l4   = lane & 15;
    const int g    = lane >> 4;          // sample group within wave
    const int w    = threadIdx.x >> 6;
    const int wid  = blockIdx.x * 4 + w;
    const int s    = wid * 4 + g;        // this lane's sample

    __shared__ float zb[4][4][8];

    // layer-2 gate angles -> SGPRs
    float qc[8], qs[8];
#pragma unroll
    for (int i = 0; i < 8; ++i) {
        float th = 0.5f * qw[8 + i];
        qc[i] = rfl(__cosf(th));
        qs[i] = rfl(__sinf(th));
    }

    // measurement signs from lane bits: lm4 = t_q & 0xF
    const int lm4[8] = {0x5, 0xF, 0xF, 0xF, 0x7, 0xB, 0x5, 0xA};
    float sg[8];
#pragma unroll
    for (int q = 0; q < 8; ++q)
        sg[q] = (__popc(l4 & lm4[q]) & 1) ? -1.0f : 1.0f;

    // phase-class sign multipliers: w=(popc(l4)+pc)&3 -> (sxm,sym)
    const int wl4 = __popc(l4);
    float sxm[4], sym[4];
#pragma unroll
    for (int pc = 0; pc < 4; ++pc) {
        const int ww = (wl4 + pc) & 3;
        sxm[pc] = (ww == 0) ? 1.0f : ((ww == 2) ? -1.0f : 0.0f);
        sym[pc] = (ww == 3) ? 1.0f : ((ww == 1) ? -1.0f : 0.0f);
    }

    // ---- load my sample's 8 packed (cos,sin) half-angle pairs ----
    const int4* hv = (const int4*)(hhu + (size_t)s * 8);
    const int4 u0 = hv[0], u1 = hv[1];
    float hcq[8], hsq[8];
#define UNPK(U, Q) do { float2 f = unpk2(U); hcq[Q] = f.x; hsq[Q] = f.y; } while (0)
    UNPK(u0.x, 0); UNPK(u0.y, 1); UNPK(u0.z, 2); UNPK(u0.w, 3);
    UNPK(u1.x, 4); UNPK(u1.y, 5); UNPK(u1.z, 6); UNPK(u1.w, 7);
#undef UNPK

    // ---- product-state init (data + layer-1 folded) ----
    // lane-bit qubits 4..7 <-> l4 bits 3..0
    float m4 = ((l4 >> 3) & 1 ? hsq[4] : hcq[4]);
    m4 *= ((l4 >> 2) & 1 ? hsq[5] : hcq[5]);
    m4 *= ((l4 >> 1) & 1 ? hsq[6] : hcq[6]);
    m4 *= ((l4 >> 0) & 1 ? hsq[7] : hcq[7]);
    // reg-bit qubits 0..3 <-> r bits 3..0
    float kf[16];
    {
        float g2[4];
        g2[0] = hcq[0]*hcq[1]; g2[1] = hcq[0]*hsq[1];
        g2[2] = hsq[0]*hcq[1]; g2[3] = hsq[0]*hsq[1];
        float g3[8];
#pragma unroll
        for (int i = 0; i < 4; ++i) { g3[2*i] = g2[i]*hcq[2]; g3[2*i+1] = g2[i]*hsq[2]; }
#pragma unroll
        for (int i = 0; i < 8; ++i) { kf[2*i] = g3[i]*hcq[3]; kf[2*i+1] = g3[i]*hsq[3]; }
    }
    float sxv[16], syv[16];
#pragma unroll
    for (int r = 0; r < 16; ++r) {
        const float rr = m4 * kf[r];
        const int pc = __popc(r) & 3;   // compile-time per unrolled r
        sxv[r] = rr * sxm[pc];
        syv[r] = rr * sym[pc];
    }

    // ---- layer 2 (qw[1]): masks R^-1(e_{7-q}), angle qw[8+j] on mask m_j ----
    RX4_REG(0xC,        qc[0], qs[0]);  // 0xC0
    RX4_REG(0x6,        qc[1], qs[1]);  // 0x60
    RX4_REG(0x3,        qc[2], qs[2]);  // 0x30
    RX4_DPP(0x1, 0x128, qc[3], qs[3]);  // 0x18: reg^1, lane xor8 = row_ror:8
    RX4_F16(0x0, 12,    qc[4], qs[4]);  // 0x0C: lane xor12
    RX4_F16(0x0, 6,     qc[5], qs[5]);  // 0x06: lane xor6
    RX4_DPP(0x0, 0x1B,  qc[6], qs[6]);  // 0x03: quad xor3
    RX4_DPP(0xC, 0xB1,  qc[7], qs[7]);  // 0xC1: reg^0xC, quad xor1

    // ---- measurement: reg-parity trees for masks {0xD,0xB,0x5,0xA} ----
    float p[16];
#pragma unroll
    for (int r = 0; r < 16; ++r) p[r] = sxv[r]*sxv[r] + syv[r]*syv[r];
    float d[8], sph[8];
#pragma unroll
    for (int e = 0; e < 8; ++e) { d[e] = p[2*e] - p[2*e+1]; sph[e] = p[2*e] + p[2*e+1]; }
    float ds[4], dd[4], sd[4];
#pragma unroll
    for (int f = 0; f < 4; ++f) {
        ds[f] = d[2*f] + d[2*f+1];
        dd[f] = d[2*f] - d[2*f+1];
        sd[f] = sph[2*f] - sph[2*f+1];
    }
    const float dsd0 = ds[0] - ds[1], dsd1 = ds[2] - ds[3];
    const float dds0 = dd[0] + dd[1], dds1 = dd[2] + dd[3];
    const float sds0 = sd[0] + sd[1], sds1 = sd[2] + sd[3];
    const float PD = dsd0 - dsd1;   // mask 0xD
    const float P5 = dsd0 + dsd1;   // mask 0x5
    const float PB = dds0 - dds1;   // mask 0xB
    const float PA = sds0 - sds1;   // mask 0xA

    float z0 = sg[0]*PD, z1 = sg[1]*PB, z2 = sg[2]*P5, z3 = sg[3]*PA;
    float z4 = sg[4]*P5, z5 = sg[5]*PA, z6 = sg[6]*P5, z7 = sg[7]*PA;

    // ---- reduce 8 values over 16 lanes (bits 0,1,2 halving; bit 3 butterfly) ----
    const bool c0 = l4 & 1, c1 = l4 & 2, c2 = l4 & 4;
    float k0 = c0 ? z1 : z0, t0 = c0 ? z0 : z1; k0 += dppf<0xB1>(t0);
    float k1 = c0 ? z3 : z2, t1 = c0 ? z2 : z3; k1 += dppf<0xB1>(t1);
    float k2 = c0 ? z5 : z4, t2 = c0 ? z4 : z5; k2 += dppf<0xB1>(t2);
    float k3 = c0 ? z7 : z6, t3 = c0 ? z6 : z7; k3 += dppf<0xB1>(t3);
    float m0 = c1 ? k1 : k0, v0 = c1 ? k0 : k1; m0 += dppf<0x4E>(v0);
    float m1 = c1 ? k3 : k2, v1 = c1 ? k2 : k3; m1 += dppf<0x4E>(v1);
    float wv = c2 ? m1 : m0, v2 = c2 ? m0 : m1; wv += __shfl_xor(v2, 4, 64);
    wv += dppf<0x128>(wv);          // xor8 within row16
    // lane l4 holds Z[l4&7] of its sample

    if (l4 < 8) zb[w][g][l4] = wv;

    // ---- out = z*W2^T + b2 for all 4 samples (W2 loaded late, after circuit) ----
    float w2r[4][8];
#pragma unroll
    for (int j = 0; j < 4; ++j)
#pragma unroll
        for (int q = 0; q < 8; ++q)
            w2r[j][q] = W2[(4 * lane + j) * 8 + q];
    const float4 b2c = *(const float4*)(b2 + 4 * lane);

#pragma unroll
    for (int gg = 0; gg < 4; ++gg) {
        const float4* zp = (const float4*)&zb[w][gg][0];
        const float4 za = zp[0], zbq = zp[1];
        const float zq[8] = {za.x, za.y, za.z, za.w, zbq.x, zbq.y, zbq.z, zbq.w};
        float o0 = b2c.x, o1 = b2c.y, o2 = b2c.z, o3 = b2c.w;
#pragma unroll
        for (int q = 0; q < 8; ++q) {
            o0 += zq[q] * w2r[0][q]; o1 += zq[q] * w2r[1][q];
            o2 += zq[q] * w2r[2][q]; o3 += zq[q] * w2r[3][q];
        }
        *(float4*)(out + (size_t)(wid * 4 + gg) * EMBED + 4 * lane) =
            make_float4(o0, o1, o2, o3);
    }
}

extern "C" void kernel_launch(void* const* d_in, const int* in_sizes, int n_in,
                              void* d_out, int out_size, void* d_ws, size_t ws_size,
                              hipStream_t stream) {
    const float* x  = (const float*)d_in[0];
    const float* W1 = (const float*)d_in[1];
    const float* b1 = (const float*)d_in[2];
    const float* qw = (const float*)d_in[3];
    const float* W2 = (const float*)d_in[4];
    const float* b2 = (const float*)d_in[5];
    float* out = (float*)d_out;
    int* hhu = (int*)d_ws;     // 65536*8 uints = 2 MB

    hipLaunchKernelGGL(h_kernel, dim3(2048), dim3(256), 0, stream, x, W1, b1, qw, hhu);
    hipLaunchKernelGGL(circ_kernel, dim3(4096), dim3(256), 0, stream,
                       hhu, qw, W2, b2, out);
}

// Round 7
// 46.618 us; speedup vs baseline: 3.6129x; 1.0292x over previous
//
#include <hip/hip_runtime.h>

#define EMBED 256
#define HITERS 4

typedef _Float16 h2v __attribute__((ext_vector_type(2)));

__device__ inline float rfl(float v) {
    return __uint_as_float(__builtin_amdgcn_readfirstlane(__float_as_uint(v)));
}
template<int CTRL>
__device__ inline float dppf(float v) {
    return __int_as_float(__builtin_amdgcn_mov_dpp(__float_as_int(v), CTRL, 0xf, 0xf, true));
}
__device__ inline float2 unpk2(int u) {
    h2v h = __builtin_bit_cast(h2v, u);
    return make_float2((float)h.x, (float)h.y);
}
__device__ inline int pk2(float a, float b) {
    return __builtin_bit_cast(int, __builtin_amdgcn_cvt_pkrtz(a, b));
}

// ---------------- phase 1: theta_q = x.W1_q + b1_q + qw[0][q] --------------
// stores packed f16 (cos th, sin th) FULL angle. wave = 2 samples/iter.
__global__ __launch_bounds__(256) void h_kernel(
    const float* __restrict__ x, const float* __restrict__ W1,
    const float* __restrict__ b1, const float* __restrict__ qw,
    int* __restrict__ hhu)
{
    const int lane = threadIdx.x & 63;
    const int wid  = blockIdx.x * 4 + (threadIdx.x >> 6);

    float4 w1c[8];
#pragma unroll
    for (int q = 0; q < 8; ++q)
        w1c[q] = *(const float4*)(W1 + q * EMBED + 4 * lane);
    const int qq = (lane >> 1) & 7;
    const float b1f = b1[qq] + qw[qq];   // + layer-1 fixed angle (RX angles add)

    const bool s0 = lane & 1, s1 = lane & 2, s2 = lane & 4, s3 = lane & 8;

    for (int it = 0; it < HITERS; ++it) {
        const int p = wid * HITERS + it;          // pair index
        const float4 x0 = *(const float4*)(x + (size_t)p * 512 + 4 * lane);
        const float4 x1 = *(const float4*)(x + (size_t)p * 512 + 256 + 4 * lane);

        float vv[16];
#pragma unroll
        for (int q = 0; q < 8; ++q) {
            vv[2*q]   = x0.x*w1c[q].x + x0.y*w1c[q].y + x0.z*w1c[q].z + x0.w*w1c[q].w;
            vv[2*q+1] = x1.x*w1c[q].x + x1.y*w1c[q].y + x1.z*w1c[q].z + x1.w*w1c[q].w;
        }
#pragma unroll
        for (int i = 0; i < 8; ++i) {   // m=1 (DPP)
            float a = vv[2*i], b = vv[2*i+1];
            float keep = s0 ? b : a, send = s0 ? a : b;
            vv[i] = keep + dppf<0xB1>(send);
        }
#pragma unroll
        for (int i = 0; i < 4; ++i) {   // m=2 (DPP)
            float a = vv[2*i], b = vv[2*i+1];
            float keep = s1 ? b : a, send = s1 ? a : b;
            vv[i] = keep + dppf<0x4E>(send);
        }
#pragma unroll
        for (int i = 0; i < 2; ++i) {   // m=4
            float a = vv[2*i], b = vv[2*i+1];
            float keep = s2 ? b : a, send = s2 ? a : b;
            vv[i] = keep + __shfl_xor(send, 4, 64);
        }
        {                               // m=8
            float a = vv[0], b = vv[1];
            float keep = s3 ? b : a, send = s3 ? a : b;
            vv[0] = keep + __shfl_xor(send, 8, 64);
        }
        float r = vv[0];
        r += __shfl_xor(r, 16, 64);
        r += __shfl_xor(r, 32, 64);     // lane holds dot for (q=(lane>>1)&7, s=lane&1)

        const float th = r + b1f;       // FULL combined angle
        const int pk = pk2(__cosf(th), __sinf(th));
        if (lane < 16)
            hhu[p * 16 + (lane & 1) * 8 + (lane >> 1)] = pk;
    }
}

// ---------------- phase 2: analytic z (thread per sample) ------------------
// z_q = sum_{S subset A_q, xor-mask(S) subset T_q} sign * prod_{j in S} sin(phi_j)
//       * prod_{j in A_q\S} cos(phi_j) * prod_{i in M_S} sin(th_i)
//       * prod_{i in T_q\M_S} cos(th_i);  sign = (-1)^((|S|+|M_S|)/2).
// Masks in qubit space (bit i = qubit i); validated against the statevector
// kernels of rounds 1-6 (same M/T sets, empirically correct).
constexpr unsigned MQ[8] = {0x03,0x06,0x0C,0x18,0x30,0x60,0xC0,0x83};
constexpr unsigned TQ[8] = {0xAB,0xFD,0xFA,0xF5,0xEA,0xD5,0xAA,0x55};
constexpr unsigned AQ[8] = {0xFE,0x03,0x07,0x0F,0x1F,0x3F,0x7F,0xFF};

__global__ __launch_bounds__(256) void z_kernel(
    int* __restrict__ wsbuf,        // in: packed f16 (cos,sin); out: z as f32
    const float* __restrict__ qw)   // (2, 8)
{
    const int s = blockIdx.x * 256 + threadIdx.x;

    const int4* hv = (const int4*)(wsbuf + (size_t)s * 8);
    const int4 a0 = hv[0], a1 = hv[1];
    float u[8], v[8];
#define UNPK(U, Q) do { float2 f = unpk2(U); u[Q] = f.x; v[Q] = f.y; } while (0)
    UNPK(a0.x, 0); UNPK(a0.y, 1); UNPK(a0.z, 2); UNPK(a0.w, 3);
    UNPK(a1.x, 4); UNPK(a1.y, 5); UNPK(a1.z, 6); UNPK(a1.w, 7);
#undef UNPK

    float qc[8], qs[8];
#pragma unroll
    for (int j = 0; j < 8; ++j) {
        const float ph = qw[8 + j];     // layer-2 full angle
        qc[j] = rfl(__cosf(ph));
        qs[j] = rfl(__sinf(ph));
    }

    float z[8];
#pragma unroll
    for (int q = 0; q < 8; ++q) {
        const unsigned Aq = AQ[q], Tq = TQ[q];
        float acc = 0.0f;
#pragma unroll
        for (unsigned S = 0; S < 256; ++S) {
            if ((S & ~Aq) != 0) continue;           // compile-time pruned
            unsigned M = 0;
#pragma unroll
            for (int j = 0; j < 8; ++j)
                if ((S >> j) & 1) M ^= MQ[j];
            if ((M & ~Tq) != 0) continue;           // compile-time pruned
            const int tot = __popc(S) + __popc(M);  // always even
            float t = ((tot >> 1) & 1) ? -1.0f : 1.0f;
#pragma unroll
            for (int j = 0; j < 8; ++j)
                if ((Aq >> j) & 1) t *= ((S >> j) & 1) ? qs[j] : qc[j];
#pragma unroll
            for (int i = 0; i < 8; ++i)
                if ((Tq >> i) & 1) t *= ((M >> i) & 1) ? v[i] : u[i];
            acc += t;
        }
        z[q] = acc;
    }

    float4* zo = (float4*)(wsbuf + (size_t)s * 8);  // overwrite in place
    zo[0] = make_float4(z[0], z[1], z[2], z[3]);
    zo[1] = make_float4(z[4], z[5], z[6], z[7]);
}

// ---------------- phase 3: out = z*W2^T + b2 (wave per 4 rows) -------------
#define ROWS_PER_WAVE 4
__global__ __launch_bounds__(256) void out_kernel(
    const float* __restrict__ zz,   // (65536, 8)
    const float* __restrict__ W2,   // (256, 8)
    const float* __restrict__ b2,   // (256,)
    float* __restrict__ out)        // (65536, 256)
{
    const int lane = threadIdx.x & 63;
    const int wv   = blockIdx.x * 4 + (threadIdx.x >> 6);

    float w2r[4][8];
#pragma unroll
    for (int j = 0; j < 4; ++j)
#pragma unroll
        for (int q = 0; q < 8; ++q)
            w2r[j][q] = W2[(4 * lane + j) * 8 + q];
    const float4 b2c = *(const float4*)(b2 + 4 * lane);

    const int sbase = wv * ROWS_PER_WAVE;
#pragma unroll
    for (int r = 0; r < ROWS_PER_WAVE; ++r) {
        const int s = sbase + r;
        const float4 za = *(const float4*)(zz + (size_t)s * 8);
        const float4 zb = *(const float4*)(zz + (size_t)s * 8 + 4);
        const float zq[8] = {za.x, za.y, za.z, za.w, zb.x, zb.y, zb.z, zb.w};
        float o0 = b2c.x, o1 = b2c.y, o2 = b2c.z, o3 = b2c.w;
#pragma unroll
        for (int q = 0; q < 8; ++q) {
            o0 += zq[q] * w2r[0][q]; o1 += zq[q] * w2r[1][q];
            o2 += zq[q] * w2r[2][q]; o3 += zq[q] * w2r[3][q];
        }
        *(float4*)(out + (size_t)s * EMBED + 4 * lane) = make_float4(o0, o1, o2, o3);
    }
}

extern "C" void kernel_launch(void* const* d_in, const int* in_sizes, int n_in,
                              void* d_out, int out_size, void* d_ws, size_t ws_size,
                              hipStream_t stream) {
    const float* x  = (const float*)d_in[0];
    const float* W1 = (const float*)d_in[1];
    const float* b1 = (const float*)d_in[2];
    const float* qw = (const float*)d_in[3];
    const float* W2 = (const float*)d_in[4];
    const float* b2 = (const float*)d_in[5];
    float* out = (float*)d_out;
    int* wsbuf = (int*)d_ws;        // 65536*8 words = 2 MB (hhu, then z in place)

    hipLaunchKernelGGL(h_kernel, dim3(2048), dim3(256), 0, stream,
                       x, W1, b1, qw, wsbuf);
    hipLaunchKernelGGL(z_kernel, dim3(256), dim3(256), 0, stream, wsbuf, qw);
    hipLaunchKernelGGL(out_kernel, dim3(4096), dim3(256), 0, stream,
                       (const float*)wsbuf, W2, b2, out);
}

// Round 8
// 43.330 us; speedup vs baseline: 3.8870x; 1.0759x over previous
//
#include <hip/hip_runtime.h>

#define EMBED 256
#define HITERS 4

typedef _Float16 h2v __attribute__((ext_vector_type(2)));

__device__ inline float rfl(float v) {
    return __uint_as_float(__builtin_amdgcn_readfirstlane(__float_as_uint(v)));
}
template<int CTRL>
__device__ inline float dppf(float v) {
    return __int_as_float(__builtin_amdgcn_mov_dpp(__float_as_int(v), CTRL, 0xf, 0xf, true));
}
__device__ inline float2 unpk2(int u) {
    h2v h = __builtin_bit_cast(h2v, u);
    return make_float2((float)h.x, (float)h.y);
}
__device__ inline int pk2(float a, float b) {
    return __builtin_bit_cast(int, __builtin_amdgcn_cvt_pkrtz(a, b));
}

// ---------------- phase 1: theta_q = x.W1_q + b1_q + qw[0][q] --------------
__global__ __launch_bounds__(256) void h_kernel(
    const float* __restrict__ x, const float* __restrict__ W1,
    const float* __restrict__ b1, const float* __restrict__ qw,
    int* __restrict__ hhu)
{
    const int lane = threadIdx.x & 63;
    const int wid  = blockIdx.x * 4 + (threadIdx.x >> 6);

    float4 w1c[8];
#pragma unroll
    for (int q = 0; q < 8; ++q)
        w1c[q] = *(const float4*)(W1 + q * EMBED + 4 * lane);
    const int qq = (lane >> 1) & 7;
    const float b1f = b1[qq] + qw[qq];   // + layer-1 fixed angle (RX angles add)

    const bool s0 = lane & 1, s1 = lane & 2, s2 = lane & 4, s3 = lane & 8;

    for (int it = 0; it < HITERS; ++it) {
        const int p = wid * HITERS + it;          // pair index
        const float4 x0 = *(const float4*)(x + (size_t)p * 512 + 4 * lane);
        const float4 x1 = *(const float4*)(x + (size_t)p * 512 + 256 + 4 * lane);

        float vv[16];
#pragma unroll
        for (int q = 0; q < 8; ++q) {
            vv[2*q]   = x0.x*w1c[q].x + x0.y*w1c[q].y + x0.z*w1c[q].z + x0.w*w1c[q].w;
            vv[2*q+1] = x1.x*w1c[q].x + x1.y*w1c[q].y + x1.z*w1c[q].z + x1.w*w1c[q].w;
        }
#pragma unroll
        for (int i = 0; i < 8; ++i) {   // m=1 (DPP)
            float a = vv[2*i], b = vv[2*i+1];
            float keep = s0 ? b : a, send = s0 ? a : b;
            vv[i] = keep + dppf<0xB1>(send);
        }
#pragma unroll
        for (int i = 0; i < 4; ++i) {   // m=2 (DPP)
            float a = vv[2*i], b = vv[2*i+1];
            float keep = s1 ? b : a, send = s1 ? a : b;
            vv[i] = keep + dppf<0x4E>(send);
        }
#pragma unroll
        for (int i = 0; i < 2; ++i) {   // m=4
            float a = vv[2*i], b = vv[2*i+1];
            float keep = s2 ? b : a, send = s2 ? a : b;
            vv[i] = keep + __shfl_xor(send, 4, 64);
        }
        {                               // m=8
            float a = vv[0], b = vv[1];
            float keep = s3 ? b : a, send = s3 ? a : b;
            vv[0] = keep + __shfl_xor(send, 8, 64);
        }
        float r = vv[0];
        r += __shfl_xor(r, 16, 64);
        r += __shfl_xor(r, 32, 64);     // lane holds dot for (q=(lane>>1)&7, s=lane&1)

        const float th = r + b1f;       // FULL combined angle
        const int pk = pk2(__cosf(th), __sinf(th));
        if (lane < 16)
            hhu[p * 16 + (lane & 1) * 8 + (lane >> 1)] = pk;
    }
}

// ---------------- phase 2: analytic z, compile-time term table -------------
constexpr unsigned MQ[8] = {0x03,0x06,0x0C,0x18,0x30,0x60,0xC0,0x83};
constexpr unsigned TQ[8] = {0xAB,0xFD,0xFA,0xF5,0xEA,0xD5,0xAA,0x55};
constexpr unsigned AQ[8] = {0xFE,0x03,0x07,0x0F,0x1F,0x3F,0x7F,0xFF};

constexpr int popc8(unsigned x) {
    int c = 0;
    for (int i = 0; i < 8; ++i) c += (x >> i) & 1;
    return c;
}
struct Term { int q; unsigned S; unsigned M; float sgn; };
struct TermTab { Term t[64]; int n; };
constexpr TermTab make_terms() {
    TermTab tt{};
    int n = 0;
    for (int q = 0; q < 8; ++q)
        for (unsigned S = 0; S < 256; ++S) {
            if ((S & ~AQ[q]) != 0) continue;
            unsigned M = 0;
            for (int j = 0; j < 8; ++j) if ((S >> j) & 1) M ^= MQ[j];
            if ((M & ~TQ[q]) != 0) continue;
            const int tot = popc8(S) + popc8(M);   // always even
            tt.t[n].q = q; tt.t[n].S = S; tt.t[n].M = M;
            tt.t[n].sgn = ((tot >> 1) & 1) ? -1.0f : 1.0f;
            ++n;
        }
    tt.n = n;
    return tt;
}
constexpr TermTab TT = make_terms();
static_assert(TT.n == 60, "term count");

__global__ __launch_bounds__(256) void z_kernel(
    int* __restrict__ wsbuf,        // in: packed f16 (cos,sin); out: z as f32
    const float* __restrict__ qw)   // (2, 8)
{
    const int s = blockIdx.x * 256 + threadIdx.x;

    const int4* hv = (const int4*)(wsbuf + (size_t)s * 8);
    const int4 a0 = hv[0], a1 = hv[1];
    float u[8], v[8];
#define UNPK(U, Q) do { float2 f = unpk2(U); u[Q] = f.x; v[Q] = f.y; } while (0)
    UNPK(a0.x, 0); UNPK(a0.y, 1); UNPK(a0.z, 2); UNPK(a0.w, 3);
    UNPK(a1.x, 4); UNPK(a1.y, 5); UNPK(a1.z, 6); UNPK(a1.w, 7);
#undef UNPK

    float qc[8], qs[8];
#pragma unroll
    for (int j = 0; j < 8; ++j) {
        const float ph = qw[8 + j];     // layer-2 full angle
        qc[j] = rfl(__cosf(ph));
        qs[j] = rfl(__sinf(ph));
    }

    float z[8] = {0,0,0,0,0,0,0,0};
#pragma unroll
    for (int t = 0; t < 60; ++t) {
        const int q = TT.t[t].q;
        const unsigned S = TT.t[t].S, M = TT.t[t].M;
        float c = TT.t[t].sgn;
#pragma unroll
        for (int j = 0; j < 8; ++j)
            if ((AQ[q] >> j) & 1) c *= ((S >> j) & 1) ? qs[j] : qc[j];
#pragma unroll
        for (int i = 0; i < 8; ++i)
            if ((TQ[q] >> i) & 1) c *= ((M >> i) & 1) ? v[i] : u[i];
        z[q] += c;
    }

    float4* zo = (float4*)(wsbuf + (size_t)s * 8);  // overwrite in place
    zo[0] = make_float4(z[0], z[1], z[2], z[3]);
    zo[1] = make_float4(z[4], z[5], z[6], z[7]);
}

// ---------------- phase 3: out = z*W2^T + b2 (wave per 4 rows) -------------
#define ROWS_PER_WAVE 4
__global__ __launch_bounds__(256) void out_kernel(
    const float* __restrict__ zz,   // (65536, 8)
    const float* __restrict__ W2,   // (256, 8)
    const float* __restrict__ b2,   // (256,)
    float* __restrict__ out)        // (65536, 256)
{
    const int lane = threadIdx.x & 63;
    const int wv   = blockIdx.x * 4 + (threadIdx.x >> 6);

    float w2r[4][8];
#pragma unroll
    for (int j = 0; j < 4; ++j)
#pragma unroll
        for (int q = 0; q < 8; ++q)
            w2r[j][q] = W2[(4 * lane + j) * 8 + q];
    const float4 b2c = *(const float4*)(b2 + 4 * lane);

    const int sbase = wv * ROWS_PER_WAVE;
#pragma unroll
    for (int r = 0; r < ROWS_PER_WAVE; ++r) {
        const int s = sbase + r;
        const float4 za = *(const float4*)(zz + (size_t)s * 8);
        const float4 zb = *(const float4*)(zz + (size_t)s * 8 + 4);
        const float zq[8] = {za.x, za.y, za.z, za.w, zb.x, zb.y, zb.z, zb.w};
        float o0 = b2c.x, o1 = b2c.y, o2 = b2c.z, o3 = b2c.w;
#pragma unroll
        for (int q = 0; q < 8; ++q) {
            o0 += zq[q] * w2r[0][q]; o1 += zq[q] * w2r[1][q];
            o2 += zq[q] * w2r[2][q]; o3 += zq[q] * w2r[3][q];
        }
        *(float4*)(out + (size_t)s * EMBED + 4 * lane) = make_float4(o0, o1, o2, o3);
    }
}

extern "C" void kernel_launch(void* const* d_in, const int* in_sizes, int n_in,
                              void* d_out, int out_size, void* d_ws, size_t ws_size,
                              hipStream_t stream) {
    const float* x  = (const float*)d_in[0];
    const float* W1 = (const float*)d_in[1];
    const float* b1 = (const float*)d_in[2];
    const float* qw = (const float*)d_in[3];
    const float* W2 = (const float*)d_in[4];
    const float* b2 = (const float*)d_in[5];
    float* out = (float*)d_out;
    int* wsbuf = (int*)d_ws;        // 65536*8 words = 2 MB (hhu, then z in place)

    hipLaunchKernelGGL(h_kernel, dim3(2048), dim3(256), 0, stream,
                       x, W1, b1, qw, wsbuf);
    hipLaunchKernelGGL(z_kernel, dim3(256), dim3(256), 0, stream, wsbuf, qw);
    hipLaunchKernelGGL(out_kernel, dim3(4096), dim3(256), 0, stream,
                       (const float*)wsbuf, W2, b2, out);
}

// Round 9
// 41.146 us; speedup vs baseline: 4.0933x; 1.0531x over previous
//
#include <hip/hip_runtime.h>

#define EMBED 256
#define BLK_SAMP 64     // samples per block
#define ASTEPS 8        // BLK_SAMP / (4 waves * 2 samples)

typedef _Float16 h2v __attribute__((ext_vector_type(2)));

__device__ inline float rfl(float v) {
    return __uint_as_float(__builtin_amdgcn_readfirstlane(__float_as_uint(v)));
}
template<int CTRL>
__device__ inline float dppf(float v) {
    return __int_as_float(__builtin_amdgcn_mov_dpp(__float_as_int(v), CTRL, 0xf, 0xf, true));
}
__device__ inline float2 unpk2(int u) {
    h2v h = __builtin_bit_cast(h2v, u);
    return make_float2((float)h.x, (float)h.y);
}
__device__ inline int pk2(float a, float b) {
    return __builtin_bit_cast(int, __builtin_amdgcn_cvt_pkrtz(a, b));
}

// ---- analytic-z compile-time term table (see R7/R8 derivation) ----
constexpr unsigned MQ[8] = {0x03,0x06,0x0C,0x18,0x30,0x60,0xC0,0x83};
constexpr unsigned TQ[8] = {0xAB,0xFD,0xFA,0xF5,0xEA,0xD5,0xAA,0x55};
constexpr unsigned AQ[8] = {0xFE,0x03,0x07,0x0F,0x1F,0x3F,0x7F,0xFF};

constexpr int popc8(unsigned x) {
    int c = 0;
    for (int i = 0; i < 8; ++i) c += (x >> i) & 1;
    return c;
}
struct Term { int q; unsigned S; unsigned M; float sgn; };
struct TermTab { Term t[64]; int n; };
constexpr TermTab make_terms() {
    TermTab tt{};
    int n = 0;
    for (int q = 0; q < 8; ++q)
        for (unsigned S = 0; S < 256; ++S) {
            if ((S & ~AQ[q]) != 0) continue;
            unsigned M = 0;
            for (int j = 0; j < 8; ++j) if ((S >> j) & 1) M ^= MQ[j];
            if ((M & ~TQ[q]) != 0) continue;
            const int tot = popc8(S) + popc8(M);   // always even
            tt.t[n].q = q; tt.t[n].S = S; tt.t[n].M = M;
            tt.t[n].sgn = ((tot >> 1) & 1) ? -1.0f : 1.0f;
            ++n;
        }
    tt.n = n;
    return tt;
}
constexpr TermTab TT = make_terms();
static_assert(TT.n == 60, "term count");

__global__ __launch_bounds__(256) void fused_kernel(
    const float* __restrict__ x,    // (65536, 256)
    const float* __restrict__ W1,   // (8, 256)
    const float* __restrict__ b1,   // (8,)
    const float* __restrict__ qw,   // (2, 8)
    const float* __restrict__ W2,   // (256, 8)
    const float* __restrict__ b2,   // (256,)
    float* __restrict__ out)        // (65536, 256)
{
    const int tid  = threadIdx.x;
    const int lane = tid & 63;
    const int w    = tid >> 6;
    const int sbase = blockIdx.x * BLK_SAMP;

    __shared__ int   hcs[8][BLK_SAMP + 1];   // [q][s] packed f16 (cos,sin); pad
    __shared__ float zf[BLK_SAMP][9];        // [s][q] z values; pad stride 9

    // ---- constants: A-phase W1 slice, C-phase W2 slice, B-phase gate trig ----
    float4 w1c[8];
#pragma unroll
    for (int q = 0; q < 8; ++q)
        w1c[q] = *(const float4*)(W1 + q * EMBED + 4 * lane);
    const int qq = lane >> 1;                 // valid for lane<16
    const float b1f = b1[qq & 7] + qw[qq & 7];  // + layer-1 RX angle (angles add)

    float w2r[4][8];
#pragma unroll
    for (int j = 0; j < 4; ++j)
#pragma unroll
        for (int q = 0; q < 8; ++q)
            w2r[j][q] = W2[(4 * lane + j) * 8 + q];
    const float4 b2c = *(const float4*)(b2 + 4 * lane);

    float qc[8], qs[8];
#pragma unroll
    for (int j = 0; j < 8; ++j) {
        const float ph = qw[8 + j];           // layer-2 full angle
        qc[j] = rfl(__cosf(ph));
        qs[j] = rfl(__sinf(ph));
    }

    const bool s0 = lane & 1, s1 = lane & 2, s2 = lane & 4, s3 = lane & 8;

    // ---- phase A: theta = x.W1^T + b1 + qw[0]; store packed (cos,sin) ----
#pragma unroll 2
    for (int step = 0; step < ASTEPS; ++step) {
        const int plocal = step * 4 + w;               // pair within block
        const int p = blockIdx.x * (BLK_SAMP / 2) + plocal;
        const float4 x0 = *(const float4*)(x + (size_t)p * 512 + 4 * lane);
        const float4 x1 = *(const float4*)(x + (size_t)p * 512 + 256 + 4 * lane);

        float vv[16];
#pragma unroll
        for (int q = 0; q < 8; ++q) {
            vv[2*q]   = x0.x*w1c[q].x + x0.y*w1c[q].y + x0.z*w1c[q].z + x0.w*w1c[q].w;
            vv[2*q+1] = x1.x*w1c[q].x + x1.y*w1c[q].y + x1.z*w1c[q].z + x1.w*w1c[q].w;
        }
#pragma unroll
        for (int i = 0; i < 8; ++i) {   // m=1 (DPP)
            float a = vv[2*i], b = vv[2*i+1];
            float keep = s0 ? b : a, send = s0 ? a : b;
            vv[i] = keep + dppf<0xB1>(send);
        }
#pragma unroll
        for (int i = 0; i < 4; ++i) {   // m=2 (DPP)
            float a = vv[2*i], b = vv[2*i+1];
            float keep = s1 ? b : a, send = s1 ? a : b;
            vv[i] = keep + dppf<0x4E>(send);
        }
#pragma unroll
        for (int i = 0; i < 2; ++i) {   // m=4
            float a = vv[2*i], b = vv[2*i+1];
            float keep = s2 ? b : a, send = s2 ? a : b;
            vv[i] = keep + __shfl_xor(send, 4, 64);
        }
        {                               // m=8
            float a = vv[0], b = vv[1];
            float keep = s3 ? b : a, send = s3 ? a : b;
            vv[0] = keep + __shfl_xor(send, 8, 64);
        }
        float r = vv[0];
        r += __shfl_xor(r, 16, 64);
        r += __shfl_xor(r, 32, 64);     // lane<16: dot for (q=lane>>1, s=lane&1)

        const float th = r + b1f;
        const int pk = pk2(__cosf(th), __sinf(th));
        if (lane < 16)
            hcs[qq][2 * plocal + (lane & 1)] = pk;
    }
    __syncthreads();

    // ---- phase B: analytic z per sample (thread s < BLK_SAMP) ----
    if (tid < BLK_SAMP) {
        const int s = tid;
        float u[8], v[8];
#pragma unroll
        for (int q = 0; q < 8; ++q) {
            const float2 f = unpk2(hcs[q][s]);
            u[q] = f.x; v[q] = f.y;
        }
        float z[8] = {0,0,0,0,0,0,0,0};
#pragma unroll
        for (int t = 0; t < 60; ++t) {
            const int q = TT.t[t].q;
            const unsigned S = TT.t[t].S, M = TT.t[t].M;
            float c = TT.t[t].sgn;
#pragma unroll
            for (int j = 0; j < 8; ++j)
                if ((AQ[q] >> j) & 1) c *= ((S >> j) & 1) ? qs[j] : qc[j];
#pragma unroll
            for (int i = 0; i < 8; ++i)
                if ((TQ[q] >> i) & 1) c *= ((M >> i) & 1) ? v[i] : u[i];
            z[q] += c;
        }
#pragma unroll
        for (int q = 0; q < 8; ++q) zf[s][q] = z[q];
    }
    __syncthreads();

    // ---- phase C: out = z.W2^T + b2, wave w writes rows [w*16, w*16+16) ----
#pragma unroll 2
    for (int i = 0; i < BLK_SAMP / 4; ++i) {
        const int sl = w * (BLK_SAMP / 4) + i;
        float zq[8];
#pragma unroll
        for (int q = 0; q < 8; ++q) zq[q] = zf[sl][q];   // LDS broadcast
        float o0 = b2c.x, o1 = b2c.y, o2 = b2c.z, o3 = b2c.w;
#pragma unroll
        for (int q = 0; q < 8; ++q) {
            o0 += zq[q] * w2r[0][q]; o1 += zq[q] * w2r[1][q];
            o2 += zq[q] * w2r[2][q]; o3 += zq[q] * w2r[3][q];
        }
        *(float4*)(out + (size_t)(sbase + sl) * EMBED + 4 * lane) =
            make_float4(o0, o1, o2, o3);
    }
}

extern "C" void kernel_launch(void* const* d_in, const int* in_sizes, int n_in,
                              void* d_out, int out_size, void* d_ws, size_t ws_size,
                              hipStream_t stream) {
    const float* x  = (const float*)d_in[0];
    const float* W1 = (const float*)d_in[1];
    const float* b1 = (const float*)d_in[2];
    const float* qw = (const float*)d_in[3];
    const float* W2 = (const float*)d_in[4];
    const float* b2 = (const float*)d_in[5];
    float* out = (float*)d_out;

    hipLaunchKernelGGL(fused_kernel, dim3(65536 / BLK_SAMP), dim3(256), 0, stream,
                       x, W1, b1, qw, W2, b2, out);
}